// Round 2
// baseline (1799.663 us; speedup 1.0000x reference)
//
#include <hip/hip_runtime.h>
#include <stdint.h>

typedef unsigned short u16;
typedef float f4 __attribute__((ext_vector_type(4)));
typedef __bf16 bf8 __attribute__((ext_vector_type(8)));

#define DEV static __device__ __forceinline__

// ---------- small math ----------
DEV u16 f2b(float f) {
    uint32_t u = __builtin_bit_cast(uint32_t, f);
    uint32_t r = (u + 0x7FFFu + ((u >> 16) & 1u)) >> 16;
    return (u16)r;
}
DEV float b2f(u16 h) {
    uint32_t u = ((uint32_t)h) << 16;
    return __builtin_bit_cast(float, u);
}
DEV float sigm(float x) { return 1.0f / (1.0f + __expf(-x)); }
DEV float tanh_f(float x) {
    float ax = fabsf(x);
    float e = __expf(-2.0f * ax);
    float r = (1.0f - e) / (1.0f + e);
    return copysignf(r, x);
}
DEV float eluf(float x) { return x > 0.0f ? x : __expf(x) - 1.0f; }

// ---------- JAX threefry2x32 (exact) ----------
#define TF_ROT(x, r) (((x) << (r)) | ((x) >> (32 - (r))))
#define TF_R4A(x0, x1) \
    x0 += x1; x1 = TF_ROT(x1, 13); x1 ^= x0; \
    x0 += x1; x1 = TF_ROT(x1, 15); x1 ^= x0; \
    x0 += x1; x1 = TF_ROT(x1, 26); x1 ^= x0; \
    x0 += x1; x1 = TF_ROT(x1, 6);  x1 ^= x0;
#define TF_R4B(x0, x1) \
    x0 += x1; x1 = TF_ROT(x1, 17); x1 ^= x0; \
    x0 += x1; x1 = TF_ROT(x1, 29); x1 ^= x0; \
    x0 += x1; x1 = TF_ROT(x1, 16); x1 ^= x0; \
    x0 += x1; x1 = TF_ROT(x1, 24); x1 ^= x0;

DEV void threefry_dev(uint32_t k0, uint32_t k1, uint32_t x0, uint32_t x1,
                      uint32_t& o0, uint32_t& o1) {
    uint32_t ks2 = k0 ^ k1 ^ 0x1BD11BDAu;
    x0 += k0; x1 += k1;
    TF_R4A(x0, x1); x0 += k1;  x1 += ks2 + 1u;
    TF_R4B(x0, x1); x0 += ks2; x1 += k0 + 2u;
    TF_R4A(x0, x1); x0 += k0;  x1 += k1 + 3u;
    TF_R4B(x0, x1); x0 += k1;  x1 += ks2 + 4u;
    TF_R4A(x0, x1); x0 += ks2; x1 += k0 + 5u;
    o0 = x0; o1 = x1;
}

static void threefry_host(uint32_t k0, uint32_t k1, uint32_t x0, uint32_t x1,
                          uint32_t& o0, uint32_t& o1) {
    uint32_t ks2 = k0 ^ k1 ^ 0x1BD11BDAu;
    x0 += k0; x1 += k1;
    TF_R4A(x0, x1); x0 += k1;  x1 += ks2 + 1u;
    TF_R4B(x0, x1); x0 += ks2; x1 += k0 + 2u;
    TF_R4A(x0, x1); x0 += k0;  x1 += k1 + 3u;
    TF_R4B(x0, x1); x0 += k1;  x1 += ks2 + 4u;
    TF_R4A(x0, x1); x0 += ks2; x1 += k0 + 5u;
    o0 = x0; o1 = x1;
}

// XLA ErfInv32 (Giles single precision)
DEV float erfinv_f(float x) {
    float w = -log1pf(-x * x);
    float p;
    if (w < 5.0f) {
        w -= 2.5f;
        p = 2.81022636e-08f;
        p = fmaf(p, w, 3.43273939e-07f);
        p = fmaf(p, w, -3.5233877e-06f);
        p = fmaf(p, w, -4.39150654e-06f);
        p = fmaf(p, w, 0.00021858087f);
        p = fmaf(p, w, -0.00125372503f);
        p = fmaf(p, w, -0.00417768164f);
        p = fmaf(p, w, 0.246640727f);
        p = fmaf(p, w, 1.50140941f);
    } else {
        w = sqrtf(w) - 3.0f;
        p = -0.000200214257f;
        p = fmaf(p, w, 0.000100950558f);
        p = fmaf(p, w, 0.00134934322f);
        p = fmaf(p, w, -0.00367342844f);
        p = fmaf(p, w, 0.00573950773f);
        p = fmaf(p, w, -0.0076224613f);
        p = fmaf(p, w, 0.00943887047f);
        p = fmaf(p, w, 1.00167406f);
        p = fmaf(p, w, 2.83297682f);
    }
    return p * x;
}

DEV float bits_to_normal(uint32_t bits) {
    uint32_t fb = (bits >> 9) | 0x3F800000u;
    float f = __builtin_bit_cast(float, fb) - 1.0f;
    const float lo = -0.99999994f;         // nextafter(-1,0)
    float u = f * 2.0f + lo;               // (hi-lo) rounds to 2.0f in f32
    u = fmaxf(lo, u);
    return 1.41421354f * erfinv_f(u);      // float32(sqrt(2))
}

// jax.random.normal draw at flat index idx — PARTITIONABLE threefry
// (jax_threefry_partitionable=True default): counter=(0, idx), bits = o0 ^ o1
DEV float tf_normal(uint32_t k0, uint32_t k1, uint32_t idx) {
    uint32_t r0, r1;
    threefry_dev(k0, k1, 0u, idx, r0, r1);
    return bits_to_normal(r0 ^ r1);
}

// ---------- workspace layout (u16 element offsets): packed weights only ----------
constexpr size_t OFF_WEMB  = 0;
constexpr size_t SZ_WEMB   = 13 * 2 * 512;
constexpr size_t OFF_WGRU  = OFF_WEMB + SZ_WEMB;
constexpr size_t SZ_WGRU   = 38 * 13 * 512;
constexpr size_t OFF_WPR1  = OFF_WGRU + SZ_WGRU;
constexpr size_t SZ_WPR1   = 13 * 7 * 512;
constexpr size_t OFF_WPR2  = OFF_WPR1 + SZ_WPR1;
constexpr size_t SZ_WPR2   = 4 * 7 * 512;
constexpr size_t OFF_WPO1D = OFF_WPR2 + SZ_WPR2;
constexpr size_t SZ_WPO1D  = 13 * 7 * 512;
constexpr size_t OFF_WPO1E = OFF_WPO1D + SZ_WPO1D;
constexpr size_t SZ_WPO1E  = 13 * 32 * 512;
constexpr size_t OFF_WPO2  = OFF_WPO1E + SZ_WPO1E;
constexpr size_t SZ_WPO2   = 4 * 7 * 512;
constexpr int PACK_TOTAL = (int)(SZ_WEMB + SZ_WGRU + SZ_WPR1 + SZ_WPR2 +
                                 SZ_WPO1D + SZ_WPO1E + SZ_WPO2);   // 601088
constexpr int PACK_BLOCKS = PACK_TOTAL / 256;                      // 2348

// embproj lives in d_out: row r=(b*64+t), float cols [380,480) = 200 bf16 (u16 cols [760,960))
// rssm_seq consumes it at step t (two barriers) before overwriting 380..580 with deter.

// ---------- weight packing into MFMA B-fragment layout ----------
// dst[((nt*ktiles + kt)*64 + lane)*8 + j] = W[kt*32 + (lane>>4)*8 + j][nt*16 + (lane&15)]
DEV void pack_one(const float* __restrict__ src, u16* __restrict__ dst,
                  int idx, int Kreal, int Nreal, int ktiles) {
    int j = idx & 7;
    int lane = (idx >> 3) & 63;
    int tile = idx >> 9;
    int kt = tile % ktiles, nt = tile / ktiles;
    int k = kt * 32 + ((lane >> 4) << 3) + j;
    int n = nt * 16 + (lane & 15);
    float v = (k < Kreal && n < Nreal) ? src[k * Nreal + n] : 0.0f;
    dst[idx] = f2b(v);
}

__global__ void pack_all(const float* w_emb, const float* w_gru,
                         const float* w_pr1, const float* w_pr2,
                         const float* w_po1, const float* w_po2, u16* ws) {
    int idx = blockIdx.x * 256 + threadIdx.x;
    if (idx < (int)SZ_WEMB) { pack_one(w_emb, ws + OFF_WEMB, idx, 36, 200, 2); return; }
    idx -= (int)SZ_WEMB;
    if (idx < (int)SZ_WGRU) { pack_one(w_gru, ws + OFF_WGRU, idx, 400, 600, 13); return; }
    idx -= (int)SZ_WGRU;
    if (idx < (int)SZ_WPR1) { pack_one(w_pr1, ws + OFF_WPR1, idx, 200, 200, 7); return; }
    idx -= (int)SZ_WPR1;
    if (idx < (int)SZ_WPR2) { pack_one(w_pr2, ws + OFF_WPR2, idx, 200, 60, 7); return; }
    idx -= (int)SZ_WPR2;
    if (idx < (int)SZ_WPO1D) { pack_one(w_po1, ws + OFF_WPO1D, idx, 200, 200, 7); return; }
    idx -= (int)SZ_WPO1D;
    if (idx < (int)SZ_WPO1E) { pack_one(w_po1 + 200 * 200, ws + OFF_WPO1E, idx, 1024, 200, 32); return; }
    idx -= (int)SZ_WPO1E;
    pack_one(w_po2, ws + OFF_WPO2, idx, 200, 60, 7);
}

// ---------- embproj: out[r, u16 760+c] = bf16( embed[r,:] @ w_po1[200:] + b_po1 ) ----------
__global__ __launch_bounds__(256, 2) void emb_proj_kernel(
    const float* __restrict__ embed, const float* __restrict__ b_po1,
    const u16* __restrict__ wpk, u16* __restrict__ outp) {
    const int tid = threadIdx.x, lane = tid & 63, rb = tid >> 6;
    const int l15 = lane & 15, l4 = lane >> 4;
    const int rbase = blockIdx.x * 64 + rb * 16;

    f4 acc[13];
#pragma unroll
    for (int nt = 0; nt < 13; ++nt) acc[nt] = (f4){0.f, 0.f, 0.f, 0.f};

    const float* arow = embed + (size_t)(rbase + l15) * 1024 + l4 * 8;
#pragma unroll 2
    for (int kt = 0; kt < 32; ++kt) {
        const float4* p = (const float4*)(arow + kt * 32);
        float4 v0 = p[0], v1 = p[1];
        bf8 a;
        a[0] = (__bf16)v0.x; a[1] = (__bf16)v0.y; a[2] = (__bf16)v0.z; a[3] = (__bf16)v0.w;
        a[4] = (__bf16)v1.x; a[5] = (__bf16)v1.y; a[6] = (__bf16)v1.z; a[7] = (__bf16)v1.w;
#pragma unroll
        for (int nt = 0; nt < 13; ++nt) {
            bf8 bb = *(const bf8*)&wpk[((nt * 32 + kt) * 64 + lane) * 8];
            acc[nt] = __builtin_amdgcn_mfma_f32_16x16x32_bf16(a, bb, acc[nt], 0, 0, 0);
        }
    }
#pragma unroll
    for (int nt = 0; nt < 13; ++nt) {
        int col = nt * 16 + l15;
        if (col < 200) {
            float bias = b_po1[col];
#pragma unroll
            for (int r = 0; r < 4; ++r) {
                int row = rbase + l4 * 4 + r;     // row = b*64 + t, same as out row
                outp[(size_t)row * 1160 + 760 + col] = f2b(acc[nt][r] + bias);
            }
        }
    }
}

// ---------- sequential RSSM scan: 64 WGs x 16 batch rows, 8 waves ----------
__global__ __launch_bounds__(512, 2) void rssm_seq(
    const float* __restrict__ action, const float* __restrict__ b_emb,
    const float* __restrict__ b_gru, const float* __restrict__ b_po2,
    const u16* __restrict__ wemb_pk, const u16* __restrict__ wgru_pk,
    const u16* __restrict__ wpo1d_pk, const u16* __restrict__ wpo2_pk,
    float* __restrict__ out, uint32_t kpo0, uint32_t kpo1) {
    __shared__ alignas(16) u16 Ax[2 * 512];       // [stoch(30)|action(6)] frags
    __shared__ alignas(16) u16 Agru[13 * 512];    // [x(200)|deter(200)] frags
    __shared__ alignas(16) u16 Apo1[7 * 512];     // deter frags
    __shared__ alignas(16) u16 Ah2[7 * 512];      // h2 frags
    __shared__ alignas(16) u16 partsm[16 * 626];  // GRU pre-activations (bf16); aliased as stats f32
    __shared__ alignas(16) float deter[16 * 200]; // f32 recurrent state
    float* stats = (float*)partsm;

    const int tid = threadIdx.x;
    const int lane = tid & 63;
    const int wave = tid >> 6;
    const int l15 = lane & 15;
    const int l4 = lane >> 4;
    const int b0 = blockIdx.x << 4;
    const u16* outp16 = (const u16*)out;

    for (int i = tid; i < 2 * 512; i += 512) Ax[i] = 0;
    for (int i = tid; i < 13 * 512; i += 512) Agru[i] = 0;
    for (int i = tid; i < 7 * 512; i += 512) Apo1[i] = 0;
    for (int i = tid; i < 7 * 512; i += 512) Ah2[i] = 0;
    for (int i = tid; i < 16 * 200; i += 512) deter[i] = 0.0f;
    __syncthreads();

    for (int t = 0; t < 64; ++t) {
        // L0: stage action into Ax (k = 30..35)
        if (tid < 96) {
            int m = tid / 6, i = tid % 6, k = 30 + i;
            float a = action[((b0 + m) * 64 + t) * 6 + i];
            int kt = k >> 5, kw = k & 31;
            Ax[(kt * 64 + (kw >> 3) * 16 + m) * 8 + (kw & 7)] = f2b(a);
        }
        __syncthreads();  // B1

        // L1: x = elu([stoch, a] @ w_emb + b_emb) -> Agru k<200
        {
            bf8 a0 = *(const bf8*)&Ax[(0 * 64 + lane) * 8];
            bf8 a1 = *(const bf8*)&Ax[(1 * 64 + lane) * 8];
            f4 acc[2];
#pragma unroll
            for (int v = 0; v < 2; ++v) acc[v] = (f4){0.f, 0.f, 0.f, 0.f};
#pragma unroll
            for (int v = 0; v < 2; ++v) {
                int nt = wave + v * 8;
                if (nt < 13) {
                    bf8 bb = *(const bf8*)&wemb_pk[((nt * 2 + 0) * 64 + lane) * 8];
                    acc[v] = __builtin_amdgcn_mfma_f32_16x16x32_bf16(a0, bb, acc[v], 0, 0, 0);
                    bb = *(const bf8*)&wemb_pk[((nt * 2 + 1) * 64 + lane) * 8];
                    acc[v] = __builtin_amdgcn_mfma_f32_16x16x32_bf16(a1, bb, acc[v], 0, 0, 0);
                }
            }
#pragma unroll
            for (int v = 0; v < 2; ++v) {
                int nt = wave + v * 8;
                if (nt < 13) {
                    int col = nt * 16 + l15;
                    if (col < 200) {
                        float bias = b_emb[col];
#pragma unroll
                        for (int r = 0; r < 4; ++r) {
                            float xv = eluf(acc[v][r] + bias);
                            int row = l4 * 4 + r;
                            int kt2 = col >> 5, kw = col & 31;
                            Agru[(kt2 * 64 + (kw >> 3) * 16 + row) * 8 + (kw & 7)] = f2b(xv);
                        }
                    }
                }
            }
        }
        __syncthreads();  // B2

        // L2: GRU GEMM: parts = [x, deter] @ w_gru
        {
            bf8 af[13];
#pragma unroll
            for (int kt = 0; kt < 13; ++kt)
                af[kt] = *(const bf8*)&Agru[(kt * 64 + lane) * 8];
            f4 acc[5];
#pragma unroll
            for (int v = 0; v < 5; ++v) acc[v] = (f4){0.f, 0.f, 0.f, 0.f};
#pragma unroll
            for (int kt = 0; kt < 13; ++kt) {
#pragma unroll
                for (int v = 0; v < 5; ++v) {
                    int nt = wave + v * 8;
                    if (nt < 38) {
                        bf8 bb = *(const bf8*)&wgru_pk[((nt * 13 + kt) * 64 + lane) * 8];
                        acc[v] = __builtin_amdgcn_mfma_f32_16x16x32_bf16(af[kt], bb, acc[v], 0, 0, 0);
                    }
                }
            }
#pragma unroll
            for (int v = 0; v < 5; ++v) {
                int nt = wave + v * 8;
                if (nt < 38) {
                    int col = nt * 16 + l15;
#pragma unroll
                    for (int r = 0; r < 4; ++r)
                        partsm[(l4 * 4 + r) * 626 + col] = f2b(acc[v][r]);
                }
            }
        }
        __syncthreads();  // B3

        // L3: GRU elementwise -> deter (LDS only); restage frags
        for (int i = tid; i < 3200; i += 512) {
            int m = i / 200, j = i % 200;
            float rg = sigm(b2f(partsm[m * 626 + j]) + b_gru[j]);
            float cg = b2f(partsm[m * 626 + 200 + j]) + b_gru[200 + j];
            cg = tanh_f(rg * cg);
            float ug = sigm(b2f(partsm[m * 626 + 400 + j]) + b_gru[400 + j] - 1.0f);
            float dn = ug * cg + (1.0f - ug) * deter[m * 200 + j];
            deter[m * 200 + j] = dn;
            u16 db = f2b(dn);
            int k = 200 + j;
            Agru[((k >> 5) * 64 + ((k & 31) >> 3) * 16 + m) * 8 + (k & 7)] = db;
            Apo1[((j >> 5) * 64 + ((j & 31) >> 3) * 16 + m) * 8 + (j & 7)] = db;
        }
        __syncthreads();  // B4

        // L4: h2 = elu(deter @ w_po1[:200] + embproj) -> Ah2
        {
            bf8 af[7];
#pragma unroll
            for (int kt = 0; kt < 7; ++kt)
                af[kt] = *(const bf8*)&Apo1[(kt * 64 + lane) * 8];
            f4 acc[2];
#pragma unroll
            for (int v = 0; v < 2; ++v) acc[v] = (f4){0.f, 0.f, 0.f, 0.f};
#pragma unroll
            for (int kt = 0; kt < 7; ++kt) {
#pragma unroll
                for (int v = 0; v < 2; ++v) {
                    int nt = wave + v * 8;
                    if (nt < 13) {
                        bf8 bb = *(const bf8*)&wpo1d_pk[((nt * 7 + kt) * 64 + lane) * 8];
                        acc[v] = __builtin_amdgcn_mfma_f32_16x16x32_bf16(af[kt], bb, acc[v], 0, 0, 0);
                    }
                }
            }
#pragma unroll
            for (int v = 0; v < 2; ++v) {
                int nt = wave + v * 8;
                if (nt < 13) {
                    int col = nt * 16 + l15;
                    if (col < 200) {
#pragma unroll
                        for (int r = 0; r < 4; ++r) {
                            int row = l4 * 4 + r;
                            float ep = b2f(outp16[(size_t)((b0 + row) * 64 + t) * 1160 + 760 + col]);
                            float h = eluf(acc[v][r] + ep);
                            Ah2[((col >> 5) * 64 + ((col & 31) >> 3) * 16 + row) * 8 + (col & 7)] = f2b(h);
                        }
                    }
                }
            }
        }
        __syncthreads();  // B5

        // L5: stats = h2 @ w_po2 (cols<60) -> stats LDS (aliases partsm)
        if (wave < 4) {
            bf8 af[7];
#pragma unroll
            for (int kt = 0; kt < 7; ++kt)
                af[kt] = *(const bf8*)&Ah2[(kt * 64 + lane) * 8];
            int nt = wave;
            f4 acc = (f4){0.f, 0.f, 0.f, 0.f};
#pragma unroll
            for (int kt = 0; kt < 7; ++kt) {
                bf8 bb = *(const bf8*)&wpo2_pk[((nt * 7 + kt) * 64 + lane) * 8];
                acc = __builtin_amdgcn_mfma_f32_16x16x32_bf16(af[kt], bb, acc, 0, 0, 0);
            }
            int col = nt * 16 + l15;
            if (col < 60) {
#pragma unroll
                for (int r = 0; r < 4; ++r)
                    stats[(l4 * 4 + r) * 64 + col] = acc[r];
            }
        }
        __syncthreads();  // B6

        // L6a: write deter to out (embproj for this (b,t) already consumed at L4)
        for (int i = tid; i < 3200; i += 512) {
            int m = i / 200, j = i % 200;
            float dn = deter[m * 200 + j];
            size_t ob = (size_t)((b0 + m) * 64 + t) * 580;
            out[ob + 90 + j] = dn;
            out[ob + 380 + j] = dn;
        }
        // L6b: posterior stats -> out; qstoch -> Ax (stoch for next step)
        for (int i = tid; i < 480; i += 512) {
            int m = i / 30, j = i % 30;
            float mean = stats[m * 64 + j] + b_po2[j];
            float raw = stats[m * 64 + 30 + j] + b_po2[30 + j];
            float sd = 2.0f * sigm(0.5f * raw) + 0.1f;
            uint32_t gi = (uint32_t)(t * 30720 + (b0 + m) * 30 + j);
            float eps = tf_normal(kpo0, kpo1, gi);
            float st = mean + sd * eps;
            size_t ob = (size_t)((b0 + m) * 64 + t) * 580;
            out[ob + j] = mean;
            out[ob + 30 + j] = sd;
            out[ob + 60 + j] = st;
            Ax[((j >> 3) * 16 + m) * 8 + (j & 7)] = f2b(st);
        }
        // next loop's B1 protects Ax before it is read
    }
}

// ---------- prior head (parallel over all (b,t)): reads deter from out ----------
__global__ __launch_bounds__(256, 2) void prior_kernel(
    float* __restrict__ out, const float* __restrict__ b_pr1,
    const float* __restrict__ b_pr2, const u16* __restrict__ wpr1_pk,
    const u16* __restrict__ wpr2_pk, uint32_t k0, uint32_t k1) {
    __shared__ alignas(16) u16 Ah[4 * 7 * 512];
    __shared__ alignas(16) float stats[4 * 16 * 64];
    const int tid = threadIdx.x, lane = tid & 63, rb = tid >> 6;
    const int l15 = lane & 15, l4 = lane >> 4;
    const int r0 = blockIdx.x * 64;

    for (int i = tid; i < 4 * 7 * 512; i += 256) Ah[i] = 0;
    __syncthreads();

    // GEMM1: h = elu(deter @ w_pr1 + b_pr1)
    {
        bf8 af[7];
        const int r = r0 + rb * 16 + l15;
#pragma unroll
        for (int kt = 0; kt < 7; ++kt) {
            int kb = kt * 32 + l4 * 8;
            bf8 a;
            if (kb < 200) {
                const float* p = out + (size_t)r * 580 + 90 + kb;
#pragma unroll
                for (int j = 0; j < 8; ++j) a[j] = (__bf16)p[j];
            } else {
#pragma unroll
                for (int j = 0; j < 8; ++j) a[j] = (__bf16)0.0f;
            }
            af[kt] = a;
        }
#pragma unroll
        for (int nt = 0; nt < 13; ++nt) {
            f4 acc = (f4){0.f, 0.f, 0.f, 0.f};
#pragma unroll
            for (int kt = 0; kt < 7; ++kt) {
                bf8 bb = *(const bf8*)&wpr1_pk[((nt * 7 + kt) * 64 + lane) * 8];
                acc = __builtin_amdgcn_mfma_f32_16x16x32_bf16(af[kt], bb, acc, 0, 0, 0);
            }
            int col = nt * 16 + l15;
            if (col < 200) {
                float bias = b_pr1[col];
#pragma unroll
                for (int rr = 0; rr < 4; ++rr) {
                    int row = l4 * 4 + rr;
                    float h = eluf(acc[rr] + bias);
                    Ah[((rb * 7 + (col >> 5)) * 64 + ((col & 31) >> 3) * 16 + row) * 8 + (col & 7)] = f2b(h);
                }
            }
        }
    }
    __syncthreads();

    // GEMM2: stats = h @ w_pr2
    {
        bf8 af[7];
#pragma unroll
        for (int kt = 0; kt < 7; ++kt)
            af[kt] = *(const bf8*)&Ah[((rb * 7 + kt) * 64 + lane) * 8];
#pragma unroll
        for (int nt = 0; nt < 4; ++nt) {
            f4 acc = (f4){0.f, 0.f, 0.f, 0.f};
#pragma unroll
            for (int kt = 0; kt < 7; ++kt) {
                bf8 bb = *(const bf8*)&wpr2_pk[((nt * 7 + kt) * 64 + lane) * 8];
                acc = __builtin_amdgcn_mfma_f32_16x16x32_bf16(af[kt], bb, acc, 0, 0, 0);
            }
            int col = nt * 16 + l15;
            if (col < 60) {
#pragma unroll
                for (int rr = 0; rr < 4; ++rr)
                    stats[(rb * 16 + l4 * 4 + rr) * 64 + col] = acc[rr];
            }
        }
    }
    __syncthreads();

    // elementwise prior stats
    for (int i = tid; i < 1920; i += 256) {
        int rl = i / 30, j = i % 30;
        float mean = stats[rl * 64 + j] + b_pr2[j];
        float raw = stats[rl * 64 + 30 + j] + b_pr2[30 + j];
        float sd = 2.0f * sigm(0.5f * raw) + 0.1f;
        int r = r0 + rl;
        int b = r >> 6, tt = r & 63;
        uint32_t gi = (uint32_t)(tt * 30720 + b * 30 + j);
        float eps = tf_normal(k0, k1, gi);
        float ps_ = mean + sd * eps;
        out[(size_t)r * 580 + 290 + j] = mean;
        out[(size_t)r * 580 + 320 + j] = sd;
        out[(size_t)r * 580 + 350 + j] = ps_;
    }
}

extern "C" void kernel_launch(void* const* d_in, const int* in_sizes, int n_in,
                              void* d_out, int out_size, void* d_ws, size_t ws_size,
                              hipStream_t stream) {
    (void)in_sizes; (void)n_in; (void)out_size; (void)ws_size;
    const float* embed = (const float*)d_in[0];
    const float* action = (const float*)d_in[1];
    // d_in[2] is_first: unused
    const float* w_emb = (const float*)d_in[3];
    const float* b_emb = (const float*)d_in[4];
    const float* w_gru = (const float*)d_in[5];
    const float* b_gru = (const float*)d_in[6];
    const float* w_pr1 = (const float*)d_in[7];
    const float* b_pr1 = (const float*)d_in[8];
    const float* w_pr2 = (const float*)d_in[9];
    const float* b_pr2 = (const float*)d_in[10];
    const float* w_po1 = (const float*)d_in[11];
    const float* b_po1 = (const float*)d_in[12];
    const float* w_po2 = (const float*)d_in[13];
    const float* b_po2 = (const float*)d_in[14];
    float* out = (float*)d_out;
    u16* ws = (u16*)d_ws;

    // posterior noise key = fold_in(key(42), 1) = threefry((0,42),(0,1))
    uint32_t kpo0, kpo1;
    threefry_host(0u, 42u, 0u, 1u, kpo0, kpo1);

    pack_all<<<PACK_BLOCKS, 256, 0, stream>>>(w_emb, w_gru, w_pr1, w_pr2, w_po1, w_po2, ws);
    emb_proj_kernel<<<1024, 256, 0, stream>>>(embed, b_po1, ws + OFF_WPO1E, (u16*)out);
    rssm_seq<<<64, 512, 0, stream>>>(action, b_emb, b_gru, b_po2,
                                     ws + OFF_WEMB, ws + OFF_WGRU, ws + OFF_WPO1D,
                                     ws + OFF_WPO2, out, kpo0, kpo1);
    prior_kernel<<<1024, 256, 0, stream>>>(out, b_pr1, b_pr2,
                                           ws + OFF_WPR1, ws + OFF_WPR2, 0u, 42u);
}